// Round 9
// baseline (244.606 us; speedup 1.0000x reference)
//
#include <hip/hip_runtime.h>
#include <math.h>

// Problem constants: N=50000, E=800000, D=H=64, ED=16.
// Pipeline v9m (R9 = MEASUREMENT ROUND; pipeline byte-identical to R8/v9,
// but gather_finalize dispatched 5x — idempotent — to measure its true
// duration: dTotal/4 = warm gather time).
//
// WHY: R8 hit the committed decision rule (total 189 >= 188). Accounting
// crisis: per-kernel models sum to ~103us vs 189 measured; ~85us hidden.
//   H1 fixed per-iteration overhead (~85us outside kernel bodies)
//      -> R9 total ~285, top-5 stays edge_mlp.
//   H2 gather actually ~90us (row-fetch model wrong for its shape)
//      -> R9 total ~550, top-5 becomes gather.
// Pre-committed R10: H2 -> rewrite gather in edge_mlp's wave-cooperative
// fetch shape; H1 -> kernel sum is near floor; polish or declare.
//
// LESSONS ENCODED:
//  - hbf must NOT alias gbf. region aliases hbf OK (dead after K2;
//    gather runs after build, so repeated gather writes to hbf are safe).
//  - edge_mlp pinned ~48.5us across 6 variants. Don't tune it.
//  - R2: random-access cost is per-EVENT; count events not bytes.
//  - R5: cg::grid.sync is O(100us)/sync here. Never.
//  - R6: dispatch boundaries ~2-5us; fusing dispatches is NOT the lever.
//  - R6/R7/R8: bin-store coalescing, cnt-hoist, slice-gather each worth
//    only 0-4us against the stuck ~189 total -> hence this measurement.
//  - cnt holds TRUE degree; max indeg ~45 (seed 0); CAP=2560 = +11 sigma.

typedef __attribute__((ext_vector_type(8))) short bf16x8;
typedef __attribute__((ext_vector_type(4))) float f32x4;

#define MAXDEG 64
#define BSHIFT 7           // 128 nodes per bucket
#define BMASK 127
#define NBUCK 391          // ceil(50000/128)
#define CAP 2560           // per-bucket region capacity (mean 2046 + 11s)
#define CHUNK 4096         // edges per bin block (16/thread)
#define BINB 196           // ceil(800000/4096)
#define BPB 40             // Bp pack blocks = 10240/256

__device__ __forceinline__ unsigned short f2b(float f) {
    unsigned u = __float_as_uint(f);
    unsigned r = (u + 0x7FFFu + ((u >> 16) & 1u)) >> 16;   // RNE
    return (unsigned short)r;
}

// K1: bin role + Bp-pack role (independent of everything downstream).
__global__ void __launch_bounds__(256) bin_pack(
        const int* __restrict__ dst, const int* __restrict__ src,
        unsigned int* __restrict__ region, int* __restrict__ gcur, int E,
        const float* __restrict__ Wm1, unsigned short* __restrict__ Bp) {
    __shared__ __align__(16) char smem[32768];
    const int bid = blockIdx.x, tid = threadIdx.x;

    if (bid < BINB) {
        // ---- bin role: histogram -> rank -> scan -> LDS sort -> run writes
        int* lc = (int*)smem;                         // [512] counts
        int* s0 = lc + 512;                           // [512] scan ping
        int* s1 = s0 + 512;                           // [512] scan pong
        int* gb = s1 + 512;                           // [512] global bases
        unsigned* lval = (unsigned*)(gb + 512);       // [4096] 16KB
        unsigned short* lbuk = (unsigned short*)(lval + 4096);  // [4096] 8KB

        for (int i = tid; i < 512; i += 256) lc[i] = 0;
        __syncthreads();

        // count + rank (16 edges/thread via 4x int4, coalesced)
        unsigned kb[16], kv[16];
#pragma unroll
        for (int j = 0; j < 4; ++j) {
            int i4 = bid * 1024 + j * 256 + tid;      // int4 index
            bool ok = (i4 * 4 < E);                   // E % 4 == 0
            int4 d4 = make_int4(0, 0, 0, 0), s4 = make_int4(0, 0, 0, 0);
            if (ok) { d4 = ((const int4*)dst)[i4]; s4 = ((const int4*)src)[i4]; }
            int dd[4] = {d4.x, d4.y, d4.z, d4.w};
            int ss[4] = {s4.x, s4.y, s4.z, s4.w};
#pragma unroll
            for (int k = 0; k < 4; ++k) {
                int idx = j * 4 + k;
                kb[idx] = 0xFFFFFFFFu;
                if (ok) {
                    int b = dd[k] >> BSHIFT;
                    int r = atomicAdd(&lc[b], 1);     // LDS atomic: local rank
                    kb[idx] = ((unsigned)b << 12) | (unsigned)r;   // b<512, r<4096
                    kv[idx] = ((unsigned)(dd[k] & BMASK) << 16) | (unsigned)ss[k];
                }
            }
        }
        __syncthreads();

        // inclusive scan (Hillis-Steele, 512 wide) -> exclusive bases in lb
        for (int i = tid; i < 512; i += 256) s0[i] = lc[i];
        __syncthreads();
        int* pin = s0; int* pout = s1;
        for (int off = 1; off < 512; off <<= 1) {
            for (int i = tid; i < 512; i += 256) {
                int v = pin[i];
                if (i >= off) v += pin[i - off];
                pout[i] = v;
            }
            __syncthreads();
            int* t = pin; pin = pout; pout = t;
        }
        int* lb = pout;   // free buffer
        for (int i = tid; i < 512; i += 256) lb[i] = pin[i] - lc[i];
        // global base reservation: ONE atomic per non-empty bucket
        for (int i = tid; i < NBUCK; i += 256) {
            int c = lc[i];
            gb[i] = c ? atomicAdd(&gcur[i], c) : 0;
        }
        __syncthreads();

        // scatter into LDS bucket-sorted order
#pragma unroll
        for (int idx = 0; idx < 16; ++idx) {
            if (kb[idx] != 0xFFFFFFFFu) {
                int b = (int)(kb[idx] >> 12), r = (int)(kb[idx] & 4095u);
                int pos = lb[b] + r;
                lval[pos] = kv[idx];
                lbuk[pos] = (unsigned short)b;
            }
        }
        __syncthreads();

        // write out: consecutive i within a bucket -> consecutive addresses
        int ne = E - bid * CHUNK; if (ne > CHUNK) ne = CHUNK;
        for (int i = tid; i < ne; i += 256) {
            int b = lbuk[i];
            int idx = gb[b] + (i - lb[b]);
            if (idx < CAP) region[(size_t)b * CAP + idx] = lval[i];
        }
    } else {
        // ---- pack Wm1 [144x64] -> Bp (5 K-steps, K padded 160) ----
        int idx = (bid - BINB) * 256 + tid;
        if (idx < 10240) {
            int j = idx & 7, ln = (idx >> 3) & 63, t = (idx >> 9) & 3, s = idx >> 11;
            int k = s * 32 + (ln >> 4) * 8 + j, col = t * 16 + (ln & 15);
            float v = (k < 144) ? Wm1[k * 64 + col] : 0.0f;
            Bp[idx] = f2b(v);
        }
    }
}

// K2: block b builds padded CSR for nodes [b*128, b*128+nb) in LDS, writes
// cnt + csr_pad as sequential streams.
__global__ void __launch_bounds__(256) build_csr(
        const unsigned int* __restrict__ region, const int* __restrict__ gcur,
        int* __restrict__ cnt, unsigned short* __restrict__ csr_pad, int N) {
    __shared__ unsigned short lcsr[128 * MAXDEG];   // 16 KB
    __shared__ int lcnt[128];
    int b = blockIdx.x, tid = threadIdx.x;
    if (tid < 128) lcnt[tid] = 0;
    __syncthreads();
    int ecnt = gcur[b]; if (ecnt > CAP) ecnt = CAP;
    const unsigned int* reg = region + (size_t)b * CAP;
    for (int i = tid; i < ecnt; i += 256) {
        unsigned v = reg[i];
        int dloc = (int)(v >> 16), s = (int)(v & 0xFFFFu);
        int r = atomicAdd(&lcnt[dloc], 1);          // true degree counted
        if (r < MAXDEG) lcsr[dloc * MAXDEG + r] = (unsigned short)s;
    }
    __syncthreads();
    int n0 = b << BSHIFT;
    int nb = N - n0; if (nb > 128) nb = 128;
    if (tid < nb) cnt[n0 + tid] = lcnt[tid];
    int4* gout = (int4*)(csr_pad + (size_t)n0 * MAXDEG);
    const int4* lin = (const int4*)lcsr;
    int tot = nb * 8;   // nb rows x 64 ushorts
    for (int i = tid; i < tot; i += 256) gout[i] = lin[i];
}

// K3: node GEMM (wave per 16 rows), self-packed W1, PRE-SCALED output:
// gbf = bf16(rsqrt(cnt+1) * (x@W1))
__global__ void __launch_bounds__(256) node_gemm_mfma(
        const float* __restrict__ x, const float* __restrict__ W1,
        const int* __restrict__ cnt, unsigned short* __restrict__ gbf, int NWT) {
    __shared__ unsigned short sB[4096];   // 8 KB
    for (int i = threadIdx.x; i < 4096; i += 256) {
        int j = i & 7, ln = (i >> 3) & 63, t = (i >> 9) & 3, s = i >> 11;
        int k = s * 32 + (ln >> 4) * 8 + j, col = t * 16 + (ln & 15);
        sB[i] = f2b(W1[k * 64 + col]);
    }
    __syncthreads();
    int wid = blockIdx.x * 4 + (threadIdx.x >> 6);
    if (wid >= NWT) return;
    int lane = threadIdx.x & 63, m = lane & 15, quad = lane >> 4;
    int r0 = wid * 16;
    f32x4 acc[4];
#pragma unroll
    for (int t = 0; t < 4; ++t) acc[t] = (f32x4){0.f, 0.f, 0.f, 0.f};
    const bf16x8* bp = (const bf16x8*)sB;
#pragma unroll
    for (int s = 0; s < 2; ++s) {
        const float4* xp = (const float4*)(x + (size_t)(r0 + m) * 64 + s * 32 + quad * 8);
        float4 v0 = xp[0], v1 = xp[1];
        bf16x8 a;
        a[0] = (short)f2b(v0.x); a[1] = (short)f2b(v0.y);
        a[2] = (short)f2b(v0.z); a[3] = (short)f2b(v0.w);
        a[4] = (short)f2b(v1.x); a[5] = (short)f2b(v1.y);
        a[6] = (short)f2b(v1.z); a[7] = (short)f2b(v1.w);
#pragma unroll
        for (int t = 0; t < 4; ++t)
            acc[t] = __builtin_amdgcn_mfma_f32_16x16x32_bf16(
                a, bp[(s * 4 + t) * 64 + lane], acc[t], 0, 0, 0);
    }
#pragma unroll
    for (int reg = 0; reg < 4; ++reg) {
        int row = r0 + quad * 4 + reg;
        float di = rsqrtf((float)cnt[row] + 1.0f);
#pragma unroll
        for (int t = 0; t < 4; ++t)
            gbf[(size_t)row * 64 + t * 16 + m] = f2b(acc[t][reg] * di);
    }
}

#define ACC8(U) \
    a0 += __uint_as_float((unsigned)(U).x << 16); \
    a1 += __uint_as_float((unsigned)(U).x & 0xffff0000u); \
    a2 += __uint_as_float((unsigned)(U).y << 16); \
    a3 += __uint_as_float((unsigned)(U).y & 0xffff0000u); \
    a4 += __uint_as_float((unsigned)(U).z << 16); \
    a5 += __uint_as_float((unsigned)(U).z & 0xffff0000u); \
    a6 += __uint_as_float((unsigned)(U).w << 16); \
    a7 += __uint_as_float((unsigned)(U).w & 0xffff0000u);

// K4: SLICE gather — thread = (node, 8-col slice). IDEMPOTENT (reads
// gbf/csr_pad/cnt, writes hbf deterministically) -> safe to dispatch 5x.
__global__ void __launch_bounds__(256) gather_finalize(
        const unsigned short* __restrict__ gbf, const unsigned short* __restrict__ csr_pad,
        const int* __restrict__ cnt, const float* __restrict__ b1,
        unsigned short* __restrict__ hbf, int N) {
    int t = blockIdx.x * 256 + threadIdx.x;
    int node = t >> 3;
    if (node >= N) return;
    int c8 = t & 7;
    int deg = cnt[node];
    if (deg > MAXDEG) deg = MAXDEG;   // never hit: max indeg ~45
    size_t base = (size_t)node << 6;
    const int4* gb4 = (const int4*)gbf;    // row stride = 8 int4 (128 B)
    float a0 = 0.f, a1 = 0.f, a2 = 0.f, a3 = 0.f,
          a4 = 0.f, a5 = 0.f, a6 = 0.f, a7 = 0.f;
    int j = 0;
    for (; j + 4 <= deg; j += 4) {
        int s0 = (int)csr_pad[base + j];
        int s1 = (int)csr_pad[base + j + 1];
        int s2 = (int)csr_pad[base + j + 2];
        int s3 = (int)csr_pad[base + j + 3];
        int4 u0 = gb4[(size_t)s0 * 8 + c8];
        int4 u1 = gb4[(size_t)s1 * 8 + c8];
        int4 u2 = gb4[(size_t)s2 * 8 + c8];
        int4 u3 = gb4[(size_t)s3 * 8 + c8];
        ACC8(u0) ACC8(u1) ACC8(u2) ACC8(u3)
    }
    for (; j < deg; ++j) {
        int s0 = (int)csr_pad[base + j];
        int4 u0 = gb4[(size_t)s0 * 8 + c8];
        ACC8(u0)
    }
    {   // self loop (g pre-scaled: agg = dd*(sum g_s + g_self))
        int4 u = gb4[(size_t)node * 8 + c8];
        ACC8(u)
    }
    float dd = rsqrtf((float)deg + 1.0f);
    const float4* bv = (const float4*)(b1 + c8 * 8);
    float4 b0 = bv[0], b14 = bv[1];
    float h0 = dd * a0 + b0.x,  h1 = dd * a1 + b0.y;
    float h2 = dd * a2 + b0.z,  h3 = dd * a3 + b0.w;
    float h4 = dd * a4 + b14.x, h5 = dd * a5 + b14.y;
    float h6 = dd * a6 + b14.z, h7 = dd * a7 + b14.w;
    h0 = h0 > 0.f ? h0 : 0.f; h1 = h1 > 0.f ? h1 : 0.f;
    h2 = h2 > 0.f ? h2 : 0.f; h3 = h3 > 0.f ? h3 : 0.f;
    h4 = h4 > 0.f ? h4 : 0.f; h5 = h5 > 0.f ? h5 : 0.f;
    h6 = h6 > 0.f ? h6 : 0.f; h7 = h7 > 0.f ? h7 : 0.f;
    int4 w;
    w.x = (int)((unsigned)f2b(h0) | ((unsigned)f2b(h1) << 16));
    w.y = (int)((unsigned)f2b(h2) | ((unsigned)f2b(h3) << 16));
    w.z = (int)((unsigned)f2b(h4) | ((unsigned)f2b(h5) << 16));
    w.w = (int)((unsigned)f2b(h6) | ((unsigned)f2b(h7) << 16));
    ((int4*)hbf)[(size_t)node * 8 + c8] = w;
}

// K5: one wave per 16 edges; K=160 (144 padded), 4 N-tiles. UNCHANGED.
__global__ void __launch_bounds__(256, 8) edge_mlp_mfma(
        const unsigned short* __restrict__ hbf, const float* __restrict__ ea,
        const int* __restrict__ src, const int* __restrict__ dst,
        const unsigned short* __restrict__ Bp,
        const float* __restrict__ bm1, const float* __restrict__ Wm2,
        const float* __restrict__ bm2, float* __restrict__ out, int E) {
    __shared__ unsigned short sB[10240];   // 20 KB
    {
        const int4* gB = (const int4*)Bp;
        int4* lB = (int4*)sB;
#pragma unroll
        for (int i = 0; i < 5; ++i)
            lB[threadIdx.x + i * 256] = gB[threadIdx.x + i * 256];
    }
    __syncthreads();
    int lane = threadIdx.x & 63;
    int wave = threadIdx.x >> 6;
    int m = lane & 15, quad = lane >> 4;
    int e0 = (blockIdx.x * 4 + wave) * 16;
    if (e0 >= E) return;
    int e = e0 + m;
    int ec = e < E ? e : E - 1;
    int si = src[ec], di = dst[ec];
    bf16x8 af[5];
    af[0] = *(const bf16x8*)(hbf + (size_t)si * 64 + quad * 8);
    af[1] = *(const bf16x8*)(hbf + (size_t)si * 64 + 32 + quad * 8);
    af[2] = *(const bf16x8*)(hbf + (size_t)di * 64 + quad * 8);
    af[3] = *(const bf16x8*)(hbf + (size_t)di * 64 + 32 + quad * 8);
    if (quad < 2) {
        const float4* ep = (const float4*)(ea + (size_t)ec * 16 + quad * 8);
        float4 v0 = ep[0], v1 = ep[1];
        af[4][0] = (short)f2b(v0.x); af[4][1] = (short)f2b(v0.y);
        af[4][2] = (short)f2b(v0.z); af[4][3] = (short)f2b(v0.w);
        af[4][4] = (short)f2b(v1.x); af[4][5] = (short)f2b(v1.y);
        af[4][6] = (short)f2b(v1.z); af[4][7] = (short)f2b(v1.w);
    } else {
#pragma unroll
        for (int j = 0; j < 8; ++j) af[4][j] = 0;
    }
    __builtin_amdgcn_sched_barrier(0);
    f32x4 acc[4];
#pragma unroll
    for (int t = 0; t < 4; ++t) acc[t] = (f32x4){0.f, 0.f, 0.f, 0.f};
    const bf16x8* bp = (const bf16x8*)sB;
#pragma unroll
    for (int s = 0; s < 5; ++s) {
#pragma unroll
        for (int t = 0; t < 4; ++t)
            acc[t] = __builtin_amdgcn_mfma_f32_16x16x32_bf16(
                af[s], bp[(s * 4 + t) * 64 + lane], acc[t], 0, 0, 0);
    }
    float w2[4], bb[4];
#pragma unroll
    for (int t = 0; t < 4; ++t) {
        int col = t * 16 + m;
        bb[t] = bm1[col];
        w2[t] = Wm2[col];
    }
    float pr[4];
#pragma unroll
    for (int r = 0; r < 4; ++r) {
        float sum = 0.0f;
#pragma unroll
        for (int t = 0; t < 4; ++t) {
            float hv = acc[t][r] + bb[t];
            sum += (hv > 0.0f ? hv : 0.0f) * w2[t];
        }
        pr[r] = sum;
    }
#pragma unroll
    for (int off = 1; off < 16; off <<= 1) {
#pragma unroll
        for (int r = 0; r < 4; ++r) pr[r] += __shfl_xor(pr[r], off, 64);
    }
    float b2 = bm2[0];
    if (m < 4) {
        int eo = e0 + quad * 4 + m;
        if (eo < E) out[eo] = 1.0f / (1.0f + __expf(-(pr[m] + b2)));
    }
}

// ================================ launcher =================================
extern "C" void kernel_launch(void* const* d_in, const int* in_sizes, int n_in,
                              void* d_out, int out_size, void* d_ws, size_t ws_size,
                              hipStream_t stream) {
    const float* x   = (const float*)d_in[0];
    const int*   src = (const int*)d_in[1];
    const int*   dst = (const int*)d_in[2];
    const float* ea  = (const float*)d_in[3];
    const float* W1  = (const float*)d_in[4];
    const float* b1  = (const float*)d_in[5];
    const float* Wm1 = (const float*)d_in[6];
    const float* bm1 = (const float*)d_in[7];
    const float* Wm2 = (const float*)d_in[8];
    const float* bm2 = (const float*)d_in[9];
    float* out = (float*)d_out;

    int N = in_sizes[0] / 64;   // 50000
    int E = in_sizes[1];        // 800000
    int NWT = N / 16;           // 3125

    // ws layout (~19.5 MB; region aliases hbf — dead before K4 writes hbf):
    char* p = (char*)d_ws;
    unsigned short* gbf     = (unsigned short*)p; p += (size_t)N * 64 * 2;      // 6.4 MB
    unsigned short* hbf     = (unsigned short*)p; p += (size_t)N * 64 * 2;      // 6.4 MB
    unsigned short* csr_pad = (unsigned short*)p; p += (size_t)N * MAXDEG * 2;  // 6.4 MB
    int*            cnt     = (int*)p;            p += (size_t)N * 4;           // 0.2 MB
    int*            gcur    = (int*)p;            p += (size_t)((NBUCK * 4 + 15) / 16) * 16;
    unsigned short* Bp      = (unsigned short*)p; p += 10240 * 2;
    unsigned int*   region  = (unsigned int*)hbf;   // 4.0 MB alias (< 6.4 MB)

    hipMemsetAsync(gcur, 0, NBUCK * sizeof(int), stream);
    bin_pack<<<BINB + BPB, 256, 0, stream>>>(dst, src, region, gcur, E, Wm1, Bp);
    build_csr<<<NBUCK, 256, 0, stream>>>(region, gcur, cnt, csr_pad, N);
    node_gemm_mfma<<<(NWT + 3) / 4, 256, 0, stream>>>(x, W1, cnt, gbf, NWT);
    // R9 MEASUREMENT: gather x5 (idempotent). dTotal/4 = warm gather dur.
    gather_finalize<<<(N * 8 + 255) / 256, 256, 0, stream>>>(gbf, csr_pad, cnt, b1, hbf, N);
    gather_finalize<<<(N * 8 + 255) / 256, 256, 0, stream>>>(gbf, csr_pad, cnt, b1, hbf, N);
    gather_finalize<<<(N * 8 + 255) / 256, 256, 0, stream>>>(gbf, csr_pad, cnt, b1, hbf, N);
    gather_finalize<<<(N * 8 + 255) / 256, 256, 0, stream>>>(gbf, csr_pad, cnt, b1, hbf, N);
    gather_finalize<<<(N * 8 + 255) / 256, 256, 0, stream>>>(gbf, csr_pad, cnt, b1, hbf, N);
    edge_mlp_mfma<<<(E + 63) / 64, 256, 0, stream>>>(hbf, ea, src, dst, Bp,
                                                     bm1, Wm2, bm2, out, E);
}